// Round 2
// baseline (340.448 us; speedup 1.0000x reference)
//
#include <hip/hip_runtime.h>
#include <stdint.h>

#define S_ 512
#define B_ 32
#define D_ 256

typedef __attribute__((ext_vector_type(8))) short bf16x8;
typedef __attribute__((ext_vector_type(4))) float f32x4;

__device__ __forceinline__ unsigned short f2bf(float f) {
    union { float f; uint32_t u; } v; v.f = f;
    uint32_t r = v.u + 0x7FFFu + ((v.u >> 16) & 1u);
    return (unsigned short)(r >> 16);
}

__device__ __forceinline__ bf16x8 ldg8(const unsigned short* p) {
    return *(const bf16x8*)p;
}

// ---------- prep 1: adj f32 -> bf16 with +1 diagonal; denomInv = 1/(rowsum+1) ----------
// one wave per adj row; grid = 3*32*512/4 blocks of 4 waves
__global__ __launch_bounds__(256) void prep_adj_kernel(
    const float* __restrict__ adj, unsigned short* __restrict__ adjBf,
    float* __restrict__ dInv)
{
    const int flat = blockIdx.x * 4 + (threadIdx.x >> 6);   // row id 0..49151
    const int lane = threadIdx.x & 63;
    const float* src = adj + (int64_t)flat * S_ + lane * 8;
    float4 v0 = ((const float4*)src)[0];
    float4 v1 = ((const float4*)src)[1];
    float sum = v0.x + v0.y + v0.z + v0.w + v1.x + v1.y + v1.z + v1.w;
#pragma unroll
    for (int o = 1; o < 64; o <<= 1) sum += __shfl_xor(sum, o);

    const int s = flat & (S_ - 1);            // row index within [S,S] block
    const int c0 = lane * 8;                  // this lane's first column
    float e0 = v0.x + ((s == c0 + 0) ? 1.f : 0.f);
    float e1 = v0.y + ((s == c0 + 1) ? 1.f : 0.f);
    float e2 = v0.z + ((s == c0 + 2) ? 1.f : 0.f);
    float e3 = v0.w + ((s == c0 + 3) ? 1.f : 0.f);
    float e4 = v1.x + ((s == c0 + 4) ? 1.f : 0.f);
    float e5 = v1.y + ((s == c0 + 5) ? 1.f : 0.f);
    float e6 = v1.z + ((s == c0 + 6) ? 1.f : 0.f);
    float e7 = v1.w + ((s == c0 + 7) ? 1.f : 0.f);
    uint4 p;
    p.x = (uint32_t)f2bf(e0) | ((uint32_t)f2bf(e1) << 16);
    p.y = (uint32_t)f2bf(e2) | ((uint32_t)f2bf(e3) << 16);
    p.z = (uint32_t)f2bf(e4) | ((uint32_t)f2bf(e5) << 16);
    p.w = (uint32_t)f2bf(e6) | ((uint32_t)f2bf(e7) << 16);
    *(uint4*)&adjBf[(int64_t)flat * S_ + c0] = p;
    if (lane == 0) dInv[flat] = 1.0f / (sum + 1.0f);
}

// ---------- prep 2: gcn [b][s][d] f32 -> XbfT [b][d][s] bf16 (tiled transpose) ----------
// grid (8, 4, 32): 64x64 tiles
__global__ __launch_bounds__(256) void prep_x_kernel(
    const float* __restrict__ gcn, unsigned short* __restrict__ XbfT)
{
    __shared__ unsigned short T[64 * 65];
    const int s0 = blockIdx.x * 64, d0 = blockIdx.y * 64, b = blockIdx.z;
    const int r = threadIdx.x >> 2, seg = threadIdx.x & 3;

    const float* src = gcn + ((int64_t)(b * S_ + s0 + r)) * D_ + d0 + seg * 16;
#pragma unroll
    for (int q = 0; q < 4; q++) {
        float4 v = ((const float4*)src)[q];
        unsigned short* t = &T[r * 65 + seg * 16 + q * 4];
        t[0] = f2bf(v.x); t[1] = f2bf(v.y); t[2] = f2bf(v.z); t[3] = f2bf(v.w);
    }
    __syncthreads();
    unsigned short tmp[16];
#pragma unroll
    for (int j = 0; j < 16; j++) tmp[j] = T[(seg * 16 + j) * 65 + r];
    unsigned short* dst = &XbfT[((int64_t)(b * D_ + d0 + r)) * S_ + s0 + seg * 16];
    ((uint4*)dst)[0] = ((uint4*)tmp)[0];
    ((uint4*)dst)[1] = ((uint4*)tmp)[1];
}

// ---------- prep 3: W, Wout -> bf16 ----------
__global__ __launch_bounds__(256) void prep_w_kernel(
    const float* __restrict__ W, const float* __restrict__ Wout,
    unsigned short* __restrict__ Wbf, unsigned short* __restrict__ WoutBf)
{
    const int i = (blockIdx.x * 256 + threadIdx.x) * 4;  // 384 blocks covers 393216
    {
        float4 v = *(const float4*)&W[i];
        uint2 p;
        p.x = (uint32_t)f2bf(v.x) | ((uint32_t)f2bf(v.y) << 16);
        p.y = (uint32_t)f2bf(v.z) | ((uint32_t)f2bf(v.w) << 16);
        *(uint2*)&Wbf[i] = p;
    }
    {
        float4 v = *(const float4*)&Wout[i];
        uint2 p;
        p.x = (uint32_t)f2bf(v.x) | ((uint32_t)f2bf(v.y) << 16);
        p.y = (uint32_t)f2bf(v.z) | ((uint32_t)f2bf(v.w) << 16);
        *(uint2*)&WoutBf[i] = p;
    }
}

// ---------- fused layer ----------
// grid (16, 32), 256 thr = 4 waves. Block tile 32 s x 256 d; wave w owns cols [64w,64w+64).
// bmm: P = (A+I)x, A/B frags straight from global (bf16, L2-served).
// mm2: Q = P @ W^T via LDS bounce of P. y = relu((Q + 2b) * dInv).
__global__ __launch_bounds__(256) void layer_kernel(
    const unsigned short* __restrict__ adjBf,   // [B][S][S] head slice, diag+1
    const unsigned short* __restrict__ xT,      // [B][D][S]
    const unsigned short* __restrict__ Wl,      // [D][D] (e-major, d contiguous)
    const float* __restrict__ bl,               // [D]
    const float* __restrict__ dInv,             // [B][S] head slice
    unsigned short* __restrict__ y,             // [B][S][D]
    unsigned short* __restrict__ yT)            // [B][D][S] or nullptr
{
    __shared__ __align__(16) unsigned short Ps[32 * 264];

    const int tid = threadIdx.x;
    const int w = tid >> 6;
    const int lm = tid & 15;
    const int g = (tid >> 4) & 3;
    const int s0 = blockIdx.x * 32;
    const int b = blockIdx.y;

    const unsigned short* adjB = adjBf + (int64_t)b * S_ * S_;
    const unsigned short* xTB  = xT + (int64_t)b * D_ * S_;

    f32x4 acc[2][4];
#pragma unroll
    for (int i = 0; i < 2; i++)
#pragma unroll
        for (int j = 0; j < 4; j++) acc[i][j] = {0.f, 0.f, 0.f, 0.f};

    for (int t0 = 0; t0 < S_; t0 += 32) {
        bf16x8 aF0 = ldg8(&adjB[(int64_t)(s0 + lm) * S_ + t0 + g * 8]);
        bf16x8 aF1 = ldg8(&adjB[(int64_t)(s0 + 16 + lm) * S_ + t0 + g * 8]);
#pragma unroll
        for (int ni = 0; ni < 4; ni++) {
            bf16x8 bF = ldg8(&xTB[(int64_t)(w * 64 + ni * 16 + lm) * S_ + t0 + g * 8]);
            acc[0][ni] = __builtin_amdgcn_mfma_f32_16x16x32_bf16(aF0, bF, acc[0][ni], 0, 0, 0);
            acc[1][ni] = __builtin_amdgcn_mfma_f32_16x16x32_bf16(aF1, bF, acc[1][ni], 0, 0, 0);
        }
    }

    // P -> Ps (bf16)
#pragma unroll
    for (int mi = 0; mi < 2; mi++)
#pragma unroll
        for (int ni = 0; ni < 4; ni++) {
            const int col = w * 64 + ni * 16 + lm;
#pragma unroll
            for (int r = 0; r < 4; r++)
                Ps[(mi * 16 + g * 4 + r) * 264 + col] = f2bf(acc[mi][ni][r]);
        }
    __syncthreads();

    // mm2: Q[s][e] = sum_d P[s][d] W[e][d]
    f32x4 acc2[2][4];
#pragma unroll
    for (int i = 0; i < 2; i++)
#pragma unroll
        for (int j = 0; j < 4; j++) acc2[i][j] = {0.f, 0.f, 0.f, 0.f};

#pragma unroll
    for (int kc = 0; kc < 8; kc++) {
        bf16x8 aF0 = *(const bf16x8*)&Ps[lm * 264 + kc * 32 + g * 8];
        bf16x8 aF1 = *(const bf16x8*)&Ps[(16 + lm) * 264 + kc * 32 + g * 8];
#pragma unroll
        for (int ni = 0; ni < 4; ni++) {
            bf16x8 bF = ldg8(&Wl[(int64_t)(w * 64 + ni * 16 + lm) * D_ + kc * 32 + g * 8]);
            acc2[0][ni] = __builtin_amdgcn_mfma_f32_16x16x32_bf16(aF0, bF, acc2[0][ni], 0, 0, 0);
            acc2[1][ni] = __builtin_amdgcn_mfma_f32_16x16x32_bf16(aF1, bF, acc2[1][ni], 0, 0, 0);
        }
    }
    __syncthreads();   // done reading P; about to overwrite Ps with y

    // epilogue: y = relu((Q + 2b) * dInv) -> Ps
    float di[2][4];
#pragma unroll
    for (int mi = 0; mi < 2; mi++)
#pragma unroll
        for (int r = 0; r < 4; r++)
            di[mi][r] = dInv[b * S_ + s0 + mi * 16 + g * 4 + r];

#pragma unroll
    for (int ni = 0; ni < 4; ni++) {
        const int col = w * 64 + ni * 16 + lm;
        const float bv = 2.0f * bl[col];
#pragma unroll
        for (int mi = 0; mi < 2; mi++)
#pragma unroll
            for (int r = 0; r < 4; r++) {
                float v = (acc2[mi][ni][r] + bv) * di[mi][r];
                v = v > 0.f ? v : 0.f;
                Ps[(mi * 16 + g * 4 + r) * 264 + col] = f2bf(v);
            }
    }
    __syncthreads();

    // coalesced stores: row-major y (64B per thread)
    {
        const int r = tid >> 3, seg = tid & 7;
        const unsigned short* srcR = &Ps[r * 264 + seg * 32];
        unsigned short* dst = &y[((int64_t)(b * S_ + s0 + r)) * D_ + seg * 32];
        ((uint4*)dst)[0] = ((const uint4*)srcR)[0];
        ((uint4*)dst)[1] = ((const uint4*)srcR)[1];
        ((uint4*)dst)[2] = ((const uint4*)srcR)[2];
        ((uint4*)dst)[3] = ((const uint4*)srcR)[3];
    }
    // transposed yT (l==0 only): thread = one e column, 64B store
    if (yT) {
        const int e = tid;
        unsigned short tmp[32];
#pragma unroll
        for (int s = 0; s < 32; s++) tmp[s] = Ps[s * 264 + e];
        unsigned short* dst = &yT[((int64_t)(b * D_ + e)) * S_ + s0];
        ((uint4*)dst)[0] = ((uint4*)tmp)[0];
        ((uint4*)dst)[1] = ((uint4*)tmp)[1];
        ((uint4*)dst)[2] = ((uint4*)tmp)[2];
        ((uint4*)dst)[3] = ((uint4*)tmp)[3];
    }
}

// ---------- final: out = gcn + b_out + concat(y) @ Wout^T ----------
// grid (16, 32), 256 thr = 4 waves, block tile 32 s x 256 e.
__global__ __launch_bounds__(256) void final_kernel(
    const unsigned short* __restrict__ yAll,   // 6 slices [B][S][D]
    const unsigned short* __restrict__ WoutBf, // [256][1536]
    const float* __restrict__ gcn,
    const float* __restrict__ bout,
    float* __restrict__ out)
{
    const int tid = threadIdx.x;
    const int w = tid >> 6;
    const int lm = tid & 15;
    const int g = (tid >> 4) & 3;
    const int s0 = blockIdx.x * 32;
    const int b = blockIdx.y;

    f32x4 acc[2][4];
#pragma unroll
    for (int i = 0; i < 2; i++)
#pragma unroll
        for (int j = 0; j < 4; j++) acc[i][j] = {0.f, 0.f, 0.f, 0.f};

#pragma unroll 2
    for (int kc = 0; kc < 48; kc++) {
        const int f0 = kc * 32;
        const int hl = f0 >> 8;
        const int e0 = f0 & 255;
        const unsigned short* yb = yAll + (int64_t)hl * (B_ * S_ * D_) + (int64_t)b * S_ * D_;
        bf16x8 aF0 = ldg8(&yb[(int64_t)(s0 + lm) * D_ + e0 + g * 8]);
        bf16x8 aF1 = ldg8(&yb[(int64_t)(s0 + 16 + lm) * D_ + e0 + g * 8]);
#pragma unroll
        for (int ni = 0; ni < 4; ni++) {
            bf16x8 bF = ldg8(&WoutBf[(int64_t)(w * 64 + ni * 16 + lm) * 1536 + f0 + g * 8]);
            acc[0][ni] = __builtin_amdgcn_mfma_f32_16x16x32_bf16(aF0, bF, acc[0][ni], 0, 0, 0);
            acc[1][ni] = __builtin_amdgcn_mfma_f32_16x16x32_bf16(aF1, bF, acc[1][ni], 0, 0, 0);
        }
    }

#pragma unroll
    for (int ni = 0; ni < 4; ni++) {
        const int e = w * 64 + ni * 16 + lm;
        const float bo = bout[e];
#pragma unroll
        for (int mi = 0; mi < 2; mi++)
#pragma unroll
            for (int r = 0; r < 4; r++) {
                const int row = mi * 16 + g * 4 + r;
                const int64_t idx = ((int64_t)(b * S_ + s0 + row)) * D_ + e;
                out[idx] = acc[mi][ni][r] + gcn[idx] + bo;
            }
    }
}

extern "C" void kernel_launch(void* const* d_in, const int* in_sizes, int n_in,
                              void* d_out, int out_size, void* d_ws, size_t ws_size,
                              hipStream_t stream) {
    const float* adj  = (const float*)d_in[0];   // [3,32,512,512]
    const float* gcn  = (const float*)d_in[1];   // [32,512,256]
    const float* W    = (const float*)d_in[4];   // [6,256,256]
    const float* bvec = (const float*)d_in[5];   // [6,256]
    const float* Wout = (const float*)d_in[6];   // [256,1536]
    const float* bout = (const float*)d_in[7];   // [256]
    float* out = (float*)d_out;

    const int64_t ADJ_N = (int64_t)3 * B_ * S_ * S_;   // 25,165,824
    const int64_t XSZ   = (int64_t)B_ * D_ * S_;       //  4,194,304
    unsigned short* adjBf  = (unsigned short*)d_ws;
    unsigned short* XbfT   = adjBf + ADJ_N;
    unsigned short* yAll   = XbfT + XSZ;               // 6 slices [B][S][D]
    unsigned short* yTh    = yAll + 6 * XSZ;           // 3 slices [B][D][S]
    unsigned short* Wbf    = yTh + 3 * XSZ;
    unsigned short* WoutBf = Wbf + 6 * D_ * D_;
    float* dInv            = (float*)(WoutBf + 6 * D_ * D_);  // [3][B][S]
    // total ≈ 136 MB (ws is 384 MiB)

    prep_adj_kernel<<<3 * B_ * S_ / 4, 256, 0, stream>>>(adj, adjBf, dInv);
    prep_x_kernel<<<dim3(8, 4, 32), 256, 0, stream>>>(gcn, XbfT);
    prep_w_kernel<<<384, 256, 0, stream>>>(W, Wout, Wbf, WoutBf);

    for (int h = 0; h < 3; h++) {
        for (int l = 0; l < 2; l++) {
            const int idx = h * 2 + l;
            layer_kernel<<<dim3(16, 32), 256, 0, stream>>>(
                adjBf + (int64_t)h * B_ * S_ * S_,
                (l == 0) ? XbfT : (yTh + (int64_t)h * XSZ),
                Wbf + (int64_t)idx * D_ * D_,
                bvec + idx * D_,
                dInv + (int64_t)h * B_ * S_,
                yAll + (int64_t)idx * XSZ,
                (l == 0) ? (yTh + (int64_t)h * XSZ) : nullptr);
        }
    }

    final_kernel<<<dim3(16, 32), 256, 0, stream>>>(yAll, WoutBf, gcn, bout, out);
}

// Round 3
// 210.680 us; speedup vs baseline: 1.6159x; 1.6159x over previous
//
#include <hip/hip_runtime.h>
#include <stdint.h>

#define S_ 512
#define B_ 32
#define D_ 256
#define XSZ ((int64_t)B_ * S_ * D_)

typedef __attribute__((ext_vector_type(8))) short bf16x8;
typedef __attribute__((ext_vector_type(4))) float f32x4;

__device__ __forceinline__ unsigned short f2bf(float f) {
    union { float f; uint32_t u; } v; v.f = f;
    uint32_t r = v.u + 0x7FFFu + ((v.u >> 16) & 1u);
    return (unsigned short)(r >> 16);
}

// async global->LDS, 16B per lane; dest must be wave-linear (base + lane*16)
__device__ __forceinline__ void gl_lds16(const unsigned short* g, unsigned short* l) {
    __builtin_amdgcn_global_load_lds(
        (const __attribute__((address_space(1))) unsigned int*)g,
        (__attribute__((address_space(3))) unsigned int*)l, 16, 0, 0);
}

// ---------- prep: gcn [b][s][d] f32 -> XbfT [b][d][s] bf16 (tiled transpose) ----------
__global__ __launch_bounds__(256) void prep_x_kernel(
    const float* __restrict__ gcn, unsigned short* __restrict__ XbfT)
{
    __shared__ unsigned short T[64 * 65];
    const int s0 = blockIdx.x * 64, d0 = blockIdx.y * 64, b = blockIdx.z;
    const int r = threadIdx.x >> 2, seg = threadIdx.x & 3;

    const float* src = gcn + ((int64_t)(b * S_ + s0 + r)) * D_ + d0 + seg * 16;
#pragma unroll
    for (int q = 0; q < 4; q++) {
        float4 v = ((const float4*)src)[q];
        unsigned short* t = &T[r * 65 + seg * 16 + q * 4];
        t[0] = f2bf(v.x); t[1] = f2bf(v.y); t[2] = f2bf(v.z); t[3] = f2bf(v.w);
    }
    __syncthreads();
    unsigned short tmp[16];
#pragma unroll
    for (int j = 0; j < 16; j++) tmp[j] = T[(seg * 16 + j) * 65 + r];
    unsigned short* dst = &XbfT[((int64_t)(b * D_ + d0 + r)) * S_ + s0 + seg * 16];
    ((uint4*)dst)[0] = ((uint4*)tmp)[0];
    ((uint4*)dst)[1] = ((uint4*)tmp)[1];
}

// ---------- prep: W, Wout -> bf16 ----------
__global__ __launch_bounds__(256) void prep_w_kernel(
    const float* __restrict__ W, const float* __restrict__ Wout,
    unsigned short* __restrict__ Wbf, unsigned short* __restrict__ WoutBf)
{
    const int i = (blockIdx.x * 256 + threadIdx.x) * 4;
    {
        float4 v = *(const float4*)&W[i];
        uint2 p;
        p.x = (uint32_t)f2bf(v.x) | ((uint32_t)f2bf(v.y) << 16);
        p.y = (uint32_t)f2bf(v.z) | ((uint32_t)f2bf(v.w) << 16);
        *(uint2*)&Wbf[i] = p;
    }
    {
        float4 v = *(const float4*)&Wout[i];
        uint2 p;
        p.x = (uint32_t)f2bf(v.x) | ((uint32_t)f2bf(v.y) << 16);
        p.y = (uint32_t)f2bf(v.z) | ((uint32_t)f2bf(v.w) << 16);
        *(uint2*)&WoutBf[i] = p;
    }
}

// ---------- fused layer ----------
// grid (16,32), 256 thr = 4 waves. Tile 32 s x 256 d; wave w owns cols [64w,64w+64).
// bmm: P = (A+I)x with A staged f32->bf16 in-reg (+rowsum), x via global_load_lds.
// mm2: Q = P @ W^T, W staged via global_load_lds. y = relu((Q+2b)/denom).
// LDS rows are 64B, stored as 4 chunks XOR-swizzled: chunk' = chunk ^ ((row>>1)&3).
template<int HAS_YT>
__global__ __launch_bounds__(256, 2) void layer_kernel(
    const float* __restrict__ adjF,          // [B][S][S] head slice f32
    const unsigned short* __restrict__ xT,   // [B][D][S] bf16
    const unsigned short* __restrict__ Wl,   // [D][D]
    const float* __restrict__ bl,            // [D]
    unsigned short* __restrict__ y,          // [B][S][D]
    unsigned short* __restrict__ yT)         // [B][D][S] (HAS_YT)
{
    __shared__ __align__(16) unsigned short bufA[2][1024];   // 32 rows x 64B
    __shared__ __align__(16) unsigned short bufB[2][8192];   // 256 rows x 64B
    __shared__ __align__(16) unsigned short Ps[32 * 264];
    __shared__ float Dsh[32];

    const int tid  = threadIdx.x;
    const int w    = tid >> 6;
    const int lane = tid & 63;
    const int lm   = lane & 15;
    const int g    = lane >> 4;
    const int s0   = blockIdx.x * 32;
    const int b    = blockIdx.y;

    const float* adjB = adjF + ((int64_t)b * S_ + s0) * S_;
    const unsigned short* xTB = xT + (int64_t)b * D_ * S_;

    // fragment read byte offsets (swizzle folded; (row>>1)&3 == (lm>>1)&3 for all our rows)
    const int sA   = (lm >> 1) & 3;
    const int aOff = lm * 64 + ((g ^ sA) << 4);
    const int bOff = (w * 64 + lm) * 64 + ((g ^ sA) << 4);

    // staging maps
    const int sr  = lane >> 2;                               // row-within-16
    const int sc8 = (((lane & 3) ^ ((lane >> 3) & 3)) << 3); // swizzled src chunk (shorts)
    const int ar  = tid >> 3;                                // A row 0..31
    const int aq  = tid & 7;                                 // 4-float chunk
    const int awz = ar * 64 + ((((aq >> 1) ^ ((ar >> 1) & 3)) << 4)) + (aq & 1) * 8;

    f32x4 acc[2][4];
#pragma unroll
    for (int i = 0; i < 2; i++)
#pragma unroll
        for (int j = 0; j < 4; j++) acc[i][j] = (f32x4){0.f, 0.f, 0.f, 0.f};

    float4 av;
    float rowsum = 0.f;

    auto stageB = [&](int t0, int bi) {
#pragma unroll
        for (int j = 0; j < 4; j++) {
            const int r = w * 64 + j * 16 + sr;
            gl_lds16(&xTB[r * S_ + t0 + sc8], &bufB[bi][(w * 4 + j) * 512 + lane * 8]);
        }
    };
    auto loadA = [&](int t0) {
        av = *(const float4*)(adjB + ar * S_ + t0 + aq * 4);
    };
    auto writeA = [&](int t0, int bi) {
        const int tc = t0 + aq * 4;
        const int srow = s0 + ar;
        float e0 = av.x + ((srow == tc    ) ? 1.f : 0.f);
        float e1 = av.y + ((srow == tc + 1) ? 1.f : 0.f);
        float e2 = av.z + ((srow == tc + 2) ? 1.f : 0.f);
        float e3 = av.w + ((srow == tc + 3) ? 1.f : 0.f);
        rowsum += e0 + e1 + e2 + e3;
        uint2 p;
        p.x = (uint32_t)f2bf(e0) | ((uint32_t)f2bf(e1) << 16);
        p.y = (uint32_t)f2bf(e2) | ((uint32_t)f2bf(e3) << 16);
        *(uint2*)((char*)bufA[bi] + awz) = p;
    };
    auto compute = [&](int bi) {
        const char* A  = (const char*)bufA[bi];
        const char* Bb = (const char*)bufB[bi];
        bf16x8 a0 = *(const bf16x8*)(A + aOff);
        bf16x8 a1 = *(const bf16x8*)(A + aOff + 1024);
#pragma unroll
        for (int ni = 0; ni < 4; ni++) {
            bf16x8 bF = *(const bf16x8*)(Bb + bOff + ni * 1024);
            acc[0][ni] = __builtin_amdgcn_mfma_f32_16x16x32_bf16(a0, bF, acc[0][ni], 0, 0, 0);
            acc[1][ni] = __builtin_amdgcn_mfma_f32_16x16x32_bf16(a1, bF, acc[1][ni], 0, 0, 0);
        }
    };

    // ---- bmm pipeline: 16 K-steps, double-buffered ----
    stageB(0, 0);
    loadA(0);
    writeA(0, 0);
    __syncthreads();

    for (int t = 0; t < 16; t++) {
        const int cur = t & 1;
        if (t < 15) { stageB((t + 1) * 32, cur ^ 1); loadA((t + 1) * 32); }
        compute(cur);
        if (t < 15) writeA((t + 1) * 32, cur ^ 1);
        __syncthreads();
    }

    // denom (sum of staged (A+I) row == adj rowsum + 1)
    rowsum += __shfl_xor(rowsum, 1);
    rowsum += __shfl_xor(rowsum, 2);
    rowsum += __shfl_xor(rowsum, 4);
    if (aq == 0) Dsh[ar] = 1.0f / rowsum;

    // P -> Ps (bf16)
#pragma unroll
    for (int mi = 0; mi < 2; mi++)
#pragma unroll
        for (int ni = 0; ni < 4; ni++) {
            const int col = w * 64 + ni * 16 + lm;
#pragma unroll
            for (int r = 0; r < 4; r++)
                Ps[(mi * 16 + g * 4 + r) * 264 + col] = f2bf(acc[mi][ni][r]);
        }

    auto stageW = [&](int kc, int bi) {
#pragma unroll
        for (int j = 0; j < 4; j++) {
            const int r = w * 64 + j * 16 + sr;
            gl_lds16(&Wl[r * D_ + kc * 32 + sc8], &bufB[bi][(w * 4 + j) * 512 + lane * 8]);
        }
    };
    stageW(0, 0);
    __syncthreads();

    // ---- mm2: 8 K-steps ----
    f32x4 acc2[2][4];
#pragma unroll
    for (int i = 0; i < 2; i++)
#pragma unroll
        for (int j = 0; j < 4; j++) acc2[i][j] = (f32x4){0.f, 0.f, 0.f, 0.f};

    for (int kc = 0; kc < 8; kc++) {
        const int cur = kc & 1;
        if (kc < 7) stageW(kc + 1, cur ^ 1);
        {
            const char* Bb = (const char*)bufB[cur];
            bf16x8 a0 = *(const bf16x8*)&Ps[lm * 264 + kc * 32 + g * 8];
            bf16x8 a1 = *(const bf16x8*)&Ps[(16 + lm) * 264 + kc * 32 + g * 8];
#pragma unroll
            for (int ni = 0; ni < 4; ni++) {
                bf16x8 bF = *(const bf16x8*)(Bb + bOff + ni * 1024);
                acc2[0][ni] = __builtin_amdgcn_mfma_f32_16x16x32_bf16(a0, bF, acc2[0][ni], 0, 0, 0);
                acc2[1][ni] = __builtin_amdgcn_mfma_f32_16x16x32_bf16(a1, bF, acc2[1][ni], 0, 0, 0);
            }
        }
        __syncthreads();
    }

    // epilogue: y = relu((Q + 2b) * dinv) -> Ps
    float dv[2][4];
#pragma unroll
    for (int mi = 0; mi < 2; mi++)
#pragma unroll
        for (int r = 0; r < 4; r++)
            dv[mi][r] = Dsh[mi * 16 + g * 4 + r];

#pragma unroll
    for (int ni = 0; ni < 4; ni++) {
        const int col = w * 64 + ni * 16 + lm;
        const float bv = 2.0f * bl[col];
#pragma unroll
        for (int mi = 0; mi < 2; mi++)
#pragma unroll
            for (int r = 0; r < 4; r++) {
                float v = (acc2[mi][ni][r] + bv) * dv[mi][r];
                v = v > 0.f ? v : 0.f;
                Ps[(mi * 16 + g * 4 + r) * 264 + col] = f2bf(v);
            }
    }
    __syncthreads();

    // coalesced y store (64B/thread)
    {
        const int rr = tid >> 3, seg = tid & 7;
        const uint4* srcp = (const uint4*)&Ps[rr * 264 + seg * 32];
        uint4* dst = (uint4*)&y[((int64_t)(b * S_ + s0 + rr)) * D_ + seg * 32];
        dst[0] = srcp[0]; dst[1] = srcp[1]; dst[2] = srcp[2]; dst[3] = srcp[3];
    }
    if (HAS_YT) {
        const int e = tid;
        unsigned short tmp[32];
#pragma unroll
        for (int s = 0; s < 32; s++) tmp[s] = Ps[s * 264 + e];
        uint4* dst = (uint4*)&yT[((int64_t)(b * D_ + e)) * S_ + s0];
        dst[0] = ((uint4*)tmp)[0]; dst[1] = ((uint4*)tmp)[1];
        dst[2] = ((uint4*)tmp)[2]; dst[3] = ((uint4*)tmp)[3];
    }
}

// ---------- final: out = gcn + b_out + concat(y) @ Wout^T ----------
// grid (16,32), same staged-dbuf skeleton, K = 48 steps.
__global__ __launch_bounds__(256, 2) void final_kernel(
    const unsigned short* __restrict__ yAll,
    const unsigned short* __restrict__ WoutBf,  // [256][1536]
    const float* __restrict__ gcn,
    const float* __restrict__ bout,
    float* __restrict__ out)
{
    __shared__ __align__(16) unsigned short bufA[2][1024];
    __shared__ __align__(16) unsigned short bufB[2][8192];

    const int tid  = threadIdx.x;
    const int w    = tid >> 6;
    const int lane = tid & 63;
    const int lm   = lane & 15;
    const int g    = lane >> 4;
    const int s0   = blockIdx.x * 32;
    const int b    = blockIdx.y;

    const int sA   = (lm >> 1) & 3;
    const int aOff = lm * 64 + ((g ^ sA) << 4);
    const int bOff = (w * 64 + lm) * 64 + ((g ^ sA) << 4);
    const int sr   = lane >> 2;
    const int sc8  = (((lane & 3) ^ ((lane >> 3) & 3)) << 3);

    const unsigned short* yBase = yAll + (int64_t)(b * S_ + s0) * D_;

    auto stage = [&](int kc, int bi) {
        const int hl = kc >> 3;
        const int f0 = (kc & 7) * 32;
        if (w < 2) {
            const int r = w * 16 + sr;
            gl_lds16(&yBase[(int64_t)hl * XSZ + r * D_ + f0 + sc8],
                     &bufA[bi][w * 512 + lane * 8]);
        }
#pragma unroll
        for (int j = 0; j < 4; j++) {
            const int r = w * 64 + j * 16 + sr;
            gl_lds16(&WoutBf[r * 1536 + kc * 32 + sc8],
                     &bufB[bi][(w * 4 + j) * 512 + lane * 8]);
        }
    };

    f32x4 acc[2][4];
#pragma unroll
    for (int i = 0; i < 2; i++)
#pragma unroll
        for (int j = 0; j < 4; j++) acc[i][j] = (f32x4){0.f, 0.f, 0.f, 0.f};

    stage(0, 0);
    __syncthreads();

    for (int kc = 0; kc < 48; kc++) {
        const int cur = kc & 1;
        if (kc < 47) stage(kc + 1, cur ^ 1);
        const char* A  = (const char*)bufA[cur];
        const char* Bb = (const char*)bufB[cur];
        bf16x8 a0 = *(const bf16x8*)(A + aOff);
        bf16x8 a1 = *(const bf16x8*)(A + aOff + 1024);
#pragma unroll
        for (int ni = 0; ni < 4; ni++) {
            bf16x8 bF = *(const bf16x8*)(Bb + bOff + ni * 1024);
            acc[0][ni] = __builtin_amdgcn_mfma_f32_16x16x32_bf16(a0, bF, acc[0][ni], 0, 0, 0);
            acc[1][ni] = __builtin_amdgcn_mfma_f32_16x16x32_bf16(a1, bF, acc[1][ni], 0, 0, 0);
        }
        __syncthreads();
    }

#pragma unroll
    for (int ni = 0; ni < 4; ni++) {
        const int e = w * 64 + ni * 16 + lm;
        const float bo = bout[e];
#pragma unroll
        for (int mi = 0; mi < 2; mi++)
#pragma unroll
            for (int r = 0; r < 4; r++) {
                const int row = mi * 16 + g * 4 + r;
                const int64_t idx = ((int64_t)(b * S_ + s0 + row)) * D_ + e;
                out[idx] = acc[mi][ni][r] + gcn[idx] + bo;
            }
    }
}

extern "C" void kernel_launch(void* const* d_in, const int* in_sizes, int n_in,
                              void* d_out, int out_size, void* d_ws, size_t ws_size,
                              hipStream_t stream) {
    const float* adj  = (const float*)d_in[0];   // [3,32,512,512]
    const float* gcn  = (const float*)d_in[1];   // [32,512,256]
    const float* W    = (const float*)d_in[4];   // [6,256,256]
    const float* bvec = (const float*)d_in[5];   // [6,256]
    const float* Wout = (const float*)d_in[6];   // [256,1536]
    const float* bout = (const float*)d_in[7];   // [256]
    float* out = (float*)d_out;

    unsigned short* XbfT   = (unsigned short*)d_ws;
    unsigned short* yAll   = XbfT + XSZ;           // 6 slices [B][S][D]
    unsigned short* yTh    = yAll + 6 * XSZ;       // 3 slices [B][D][S]
    unsigned short* Wbf    = yTh + 3 * XSZ;
    unsigned short* WoutBf = Wbf + 6 * D_ * D_;
    // ~85 MB of the 384 MiB workspace

    prep_x_kernel<<<dim3(8, 4, 32), 256, 0, stream>>>(gcn, XbfT);
    prep_w_kernel<<<384, 256, 0, stream>>>(W, Wout, Wbf, WoutBf);

    for (int h = 0; h < 3; h++) {
        const float* adjH = adj + (int64_t)h * B_ * S_ * S_;
        // l = 0: x source = XbfT, emits yT for l=1
        layer_kernel<1><<<dim3(16, 32), 256, 0, stream>>>(
            adjH, XbfT,
            Wbf + (int64_t)(h * 2 + 0) * D_ * D_, bvec + (h * 2 + 0) * D_,
            yAll + (int64_t)(h * 2 + 0) * XSZ, yTh + (int64_t)h * XSZ);
        // l = 1: x source = yT of l=0
        layer_kernel<0><<<dim3(16, 32), 256, 0, stream>>>(
            adjH, yTh + (int64_t)h * XSZ,
            Wbf + (int64_t)(h * 2 + 1) * D_ * D_, bvec + (h * 2 + 1) * D_,
            yAll + (int64_t)(h * 2 + 1) * XSZ, nullptr);
    }

    final_kernel<<<dim3(16, 32), 256, 0, stream>>>(yAll, WoutBf, gcn, bout, out);
}

// Round 4
// 169.052 us; speedup vs baseline: 2.0139x; 1.2462x over previous
//
#include <hip/hip_runtime.h>
#include <stdint.h>

#define S_ 512
#define B_ 32
#define D_ 256
#define XSZ ((int64_t)B_ * S_ * D_)

typedef __attribute__((ext_vector_type(8))) short bf16x8;
typedef __attribute__((ext_vector_type(4))) float f32x4;

#define WAITVM(n) asm volatile("s_waitcnt vmcnt(" #n ")" ::: "memory")
#define SCHEDB() __builtin_amdgcn_sched_barrier(0)
#define BAR() __builtin_amdgcn_s_barrier()

__device__ __forceinline__ unsigned short f2bf(float f) {
    union { float f; uint32_t u; } v; v.f = f;
    uint32_t r = v.u + 0x7FFFu + ((v.u >> 16) & 1u);
    return (unsigned short)(r >> 16);
}

// async global->LDS: 64 lanes x 16B; LDS dest = wave-uniform base + lane*16
__device__ __forceinline__ void gl_lds16(const unsigned short* g, void* lds_base) {
    __builtin_amdgcn_global_load_lds(
        (const __attribute__((address_space(1))) unsigned int*)g,
        (__attribute__((address_space(3))) unsigned int*)lds_base, 16, 0, 0);
}

__device__ __forceinline__ f32x4 MF(bf16x8 a, bf16x8 b, f32x4 c) {
    return __builtin_amdgcn_mfma_f32_16x16x32_bf16(a, b, c, 0, 0, 0);
}

// ---------- prep: adj f32 -> bf16 with +1 diagonal; dInv = 1/(rowsum+1) ----------
__global__ __launch_bounds__(256) void prep_adj_kernel(
    const float* __restrict__ adj, unsigned short* __restrict__ adjBf,
    float* __restrict__ dInv)
{
    const int flat = blockIdx.x * 4 + (threadIdx.x >> 6);   // row id over [3][B][S]
    const int lane = threadIdx.x & 63;
    const float* src = adj + (int64_t)flat * S_ + lane * 8;
    float4 v0 = ((const float4*)src)[0];
    float4 v1 = ((const float4*)src)[1];
    float sum = v0.x + v0.y + v0.z + v0.w + v1.x + v1.y + v1.z + v1.w;
#pragma unroll
    for (int o = 1; o < 64; o <<= 1) sum += __shfl_xor(sum, o);

    const int s = flat & (S_ - 1);
    const int c0 = lane * 8;
    float e0 = v0.x + ((s == c0 + 0) ? 1.f : 0.f);
    float e1 = v0.y + ((s == c0 + 1) ? 1.f : 0.f);
    float e2 = v0.z + ((s == c0 + 2) ? 1.f : 0.f);
    float e3 = v0.w + ((s == c0 + 3) ? 1.f : 0.f);
    float e4 = v1.x + ((s == c0 + 4) ? 1.f : 0.f);
    float e5 = v1.y + ((s == c0 + 5) ? 1.f : 0.f);
    float e6 = v1.z + ((s == c0 + 6) ? 1.f : 0.f);
    float e7 = v1.w + ((s == c0 + 7) ? 1.f : 0.f);
    uint4 p;
    p.x = (uint32_t)f2bf(e0) | ((uint32_t)f2bf(e1) << 16);
    p.y = (uint32_t)f2bf(e2) | ((uint32_t)f2bf(e3) << 16);
    p.z = (uint32_t)f2bf(e4) | ((uint32_t)f2bf(e5) << 16);
    p.w = (uint32_t)f2bf(e6) | ((uint32_t)f2bf(e7) << 16);
    *(uint4*)&adjBf[(int64_t)flat * S_ + c0] = p;
    if (lane == 0) dInv[flat] = 1.0f / (sum + 1.0f);
}

// ---------- prep: gcn [b][s][d] f32 -> XbfT [b][d][s] bf16 ----------
__global__ __launch_bounds__(256) void prep_x_kernel(
    const float* __restrict__ gcn, unsigned short* __restrict__ XbfT)
{
    __shared__ unsigned short T[64 * 65];
    const int s0 = blockIdx.x * 64, d0 = blockIdx.y * 64, b = blockIdx.z;
    const int r = threadIdx.x >> 2, seg = threadIdx.x & 3;

    const float* src = gcn + ((int64_t)(b * S_ + s0 + r)) * D_ + d0 + seg * 16;
#pragma unroll
    for (int q = 0; q < 4; q++) {
        float4 v = ((const float4*)src)[q];
        unsigned short* t = &T[r * 65 + seg * 16 + q * 4];
        t[0] = f2bf(v.x); t[1] = f2bf(v.y); t[2] = f2bf(v.z); t[3] = f2bf(v.w);
    }
    __syncthreads();
    unsigned short tmp[16];
#pragma unroll
    for (int j = 0; j < 16; j++) tmp[j] = T[(seg * 16 + j) * 65 + r];
    unsigned short* dst = &XbfT[((int64_t)(b * D_ + d0 + r)) * S_ + s0 + seg * 16];
    ((uint4*)dst)[0] = ((uint4*)tmp)[0];
    ((uint4*)dst)[1] = ((uint4*)tmp)[1];
}

// ---------- prep: W, Wout -> bf16 ----------
__global__ __launch_bounds__(256) void prep_w_kernel(
    const float* __restrict__ W, const float* __restrict__ Wout,
    unsigned short* __restrict__ Wbf, unsigned short* __restrict__ WoutBf)
{
    const int i = (blockIdx.x * 256 + threadIdx.x) * 4;
    {
        float4 v = *(const float4*)&W[i];
        uint2 p;
        p.x = (uint32_t)f2bf(v.x) | ((uint32_t)f2bf(v.y) << 16);
        p.y = (uint32_t)f2bf(v.z) | ((uint32_t)f2bf(v.w) << 16);
        *(uint2*)&Wbf[i] = p;
    }
    {
        float4 v = *(const float4*)&Wout[i];
        uint2 p;
        p.x = (uint32_t)f2bf(v.x) | ((uint32_t)f2bf(v.y) << 16);
        p.y = (uint32_t)f2bf(v.z) | ((uint32_t)f2bf(v.w) << 16);
        *(uint2*)&WoutBf[i] = p;
    }
}

// ---------- fused layer ----------
// 512 blocks (XCD-chunked), 4 waves. Tile 32 s x 256 d. BK=64 bmm (8 steps),
// BK=32 mm2 (8 steps). Counted-vmcnt pipeline, 128B LDS rows with 8-chunk XOR swizzle.
template<int HAS_YT>
__global__ __launch_bounds__(256, 2) void layer_kernel(
    const unsigned short* __restrict__ adjBf_h,  // [B][S][S] head slice (diag+1)
    const unsigned short* __restrict__ xT,       // [B][D][S]
    const unsigned short* __restrict__ Wl,       // [D][D]
    const float* __restrict__ bl,                // [D]
    const float* __restrict__ dInvH,             // [B][S]
    unsigned short* __restrict__ y,              // [B][S][D]
    unsigned short* __restrict__ yT)             // [B][D][S]
{
    __shared__ __align__(16) char smem[73728];
    // bmm: bufA = smem + cur*4096 (32x128B), bufB = smem + 8192 + cur*32768 (256x128B)
    // mm2 overlay: Ps = smem[0..16896), Wst = smem + 17408 + cur*16384 (256x64B)

    const int tid = threadIdx.x;
    const int w   = tid >> 6;
    const int l   = tid & 63;
    const int lm  = l & 15;
    const int g   = l >> 4;

    int flat = blockIdx.y * 16 + blockIdx.x;
    flat = (flat & 7) * 64 + (flat >> 3);        // XCD-chunked remap (512 = 8*64, bijective)
    const int b  = flat >> 4;
    const int s0 = (flat & 15) * 32;

    const unsigned short* adjB = adjBf_h + ((int64_t)b * S_ + s0) * S_;
    const unsigned short* xTB  = xT + (int64_t)b * D_ * S_;

    const int srow8  = l >> 3;                   // row-in-8 for 128B-row staging
    const int schunk = ((l & 7) ^ (l >> 3)) * 8; // pre-swizzled source col (shorts)

    f32x4 acc[2][4];
#pragma unroll
    for (int i = 0; i < 2; i++)
#pragma unroll
        for (int j = 0; j < 4; j++) acc[i][j] = (f32x4){0.f, 0.f, 0.f, 0.f};

    auto stage = [&](int t0, int cur) {          // 9 gl_lds per wave
        char* bA = smem + cur * 4096;
        char* bB = smem + 8192 + cur * 32768;
        gl_lds16(&adjB[(w * 8 + srow8) * S_ + t0 + schunk], bA + w * 1024);
#pragma unroll
        for (int j = 0; j < 8; j++)
            gl_lds16(&xTB[(w * 64 + j * 8 + srow8) * S_ + t0 + schunk],
                     bB + w * 8192 + j * 1024);
    };
    auto compute = [&](int cur) {
        const char* bA = smem + cur * 4096;
        const char* bB = smem + 8192 + cur * 32768;
#pragma unroll
        for (int h = 0; h < 2; h++) {
            const int co = ((h * 4 + g) ^ (lm & 7)) * 16;
            bf16x8 a0 = *(const bf16x8*)(bA + lm * 128 + co);
            bf16x8 a1 = *(const bf16x8*)(bA + (16 + lm) * 128 + co);
#pragma unroll
            for (int ni = 0; ni < 4; ni++) {
                bf16x8 bF = *(const bf16x8*)(bB + (w * 64 + ni * 16 + lm) * 128 + co);
                acc[0][ni] = MF(a0, bF, acc[0][ni]);
                acc[1][ni] = MF(a1, bF, acc[1][ni]);
            }
        }
    };

    // ---- bmm: P = (A+I)x, 8 steps of BK=64, counted vmcnt ----
    stage(0, 0);
    for (int t = 0; t < 8; t++) {
        const int cur = t & 1;
        if (t < 7) { stage((t + 1) * 64, cur ^ 1); WAITVM(9); }
        else       { WAITVM(0); }
        SCHEDB(); BAR(); SCHEDB();
        compute(cur);
        SCHEDB(); BAR();
    }

    // ---- P -> Ps (bf16), stage W tile 0 ----
    unsigned short* Ps = (unsigned short*)smem;
#pragma unroll
    for (int mi = 0; mi < 2; mi++)
#pragma unroll
        for (int ni = 0; ni < 4; ni++) {
            const int col = w * 64 + ni * 16 + lm;
#pragma unroll
            for (int r = 0; r < 4; r++)
                Ps[(mi * 16 + g * 4 + r) * 264 + col] = f2bf(acc[mi][ni][r]);
        }

    const int sr16 = l >> 2;                         // row-in-16 for 64B-row staging
    const int sc4  = ((l & 3) ^ ((l >> 3) & 3)) * 8; // 4-chunk swizzle source col
    auto stageW = [&](int kc, int cur) {             // 4 gl_lds per wave
        char* bW = smem + 17408 + cur * 16384;
#pragma unroll
        for (int j = 0; j < 4; j++)
            gl_lds16(&Wl[(w * 64 + j * 16 + sr16) * D_ + kc * 32 + sc4],
                     bW + w * 4096 + j * 1024);
    };
    stageW(0, 0);
    __syncthreads();

    // ---- mm2: Q = P @ W^T, 8 steps of BK=32 ----
    f32x4 acc2[2][4];
#pragma unroll
    for (int i = 0; i < 2; i++)
#pragma unroll
        for (int j = 0; j < 4; j++) acc2[i][j] = (f32x4){0.f, 0.f, 0.f, 0.f};

    for (int kc = 0; kc < 8; kc++) {
        const int cur = kc & 1;
        if (kc < 7) { stageW(kc + 1, cur ^ 1); WAITVM(4); }
        else        { WAITVM(0); }
        SCHEDB(); BAR(); SCHEDB();
        {
            const char* bW = smem + 17408 + cur * 16384;
            bf16x8 a0 = *(const bf16x8*)&Ps[lm * 264 + kc * 32 + g * 8];
            bf16x8 a1 = *(const bf16x8*)&Ps[(16 + lm) * 264 + kc * 32 + g * 8];
            const int co2 = (g ^ ((lm >> 1) & 3)) << 4;
#pragma unroll
            for (int ni = 0; ni < 4; ni++) {
                bf16x8 bF = *(const bf16x8*)(bW + (w * 64 + ni * 16 + lm) * 64 + co2);
                acc2[0][ni] = MF(a0, bF, acc2[0][ni]);
                acc2[1][ni] = MF(a1, bF, acc2[1][ni]);
            }
        }
        SCHEDB(); BAR();
    }

    // ---- epilogue: y = relu((Q + 2b) * dInv) ----
    float dv[2][4];
#pragma unroll
    for (int mi = 0; mi < 2; mi++)
#pragma unroll
        for (int r = 0; r < 4; r++)
            dv[mi][r] = dInvH[b * S_ + s0 + mi * 16 + g * 4 + r];

#pragma unroll
    for (int ni = 0; ni < 4; ni++) {
        const int col = w * 64 + ni * 16 + lm;
        const float bv = 2.0f * bl[col];
#pragma unroll
        for (int mi = 0; mi < 2; mi++)
#pragma unroll
            for (int r = 0; r < 4; r++) {
                float v = (acc2[mi][ni][r] + bv) * dv[mi][r];
                v = v > 0.f ? v : 0.f;
                Ps[(mi * 16 + g * 4 + r) * 264 + col] = f2bf(v);
            }
    }
    __syncthreads();

    {
        const int rr = tid >> 3, seg = tid & 7;
        const uint4* srcp = (const uint4*)&Ps[rr * 264 + seg * 32];
        uint4* dst = (uint4*)&y[((int64_t)(b * S_ + s0 + rr)) * D_ + seg * 32];
        dst[0] = srcp[0]; dst[1] = srcp[1]; dst[2] = srcp[2]; dst[3] = srcp[3];
    }
    if (HAS_YT) {
        const int e = tid;
        unsigned short tmp[32];
#pragma unroll
        for (int s = 0; s < 32; s++) tmp[s] = Ps[s * 264 + e];
        uint4* dst = (uint4*)&yT[((int64_t)(b * D_ + e)) * S_ + s0];
        dst[0] = ((uint4*)tmp)[0]; dst[1] = ((uint4*)tmp)[1];
        dst[2] = ((uint4*)tmp)[2]; dst[3] = ((uint4*)tmp)[3];
    }
}

// ---------- final: out = gcn + b_out + concat(y) @ Wout^T ----------
// Same counted skeleton, BK=64, 24 steps.
__global__ __launch_bounds__(256, 2) void final_kernel(
    const unsigned short* __restrict__ yAll,
    const unsigned short* __restrict__ WoutBf,  // [256][1536]
    const float* __restrict__ gcn,
    const float* __restrict__ bout,
    float* __restrict__ out)
{
    __shared__ __align__(16) char smem[73728];

    const int tid = threadIdx.x;
    const int w   = tid >> 6;
    const int l   = tid & 63;
    const int lm  = l & 15;
    const int g   = l >> 4;
    const int s0  = blockIdx.x * 32;
    const int b   = blockIdx.y;

    const int srow8  = l >> 3;
    const int schunk = ((l & 7) ^ (l >> 3)) * 8;

    auto stage = [&](int kc, int cur) {          // 9 gl_lds per wave
        char* bA = smem + cur * 4096;
        char* bB = smem + 8192 + cur * 32768;
        const int hl = kc >> 2;
        const int e0 = (kc & 3) * 64;
        gl_lds16(&yAll[(int64_t)hl * XSZ +
                       ((int64_t)(b * S_ + s0) + w * 8 + srow8) * D_ + e0 + schunk],
                 bA + w * 1024);
#pragma unroll
        for (int j = 0; j < 8; j++)
            gl_lds16(&WoutBf[(w * 64 + j * 8 + srow8) * 1536 + kc * 64 + schunk],
                     bB + w * 8192 + j * 1024);
    };

    f32x4 acc[2][4];
#pragma unroll
    for (int i = 0; i < 2; i++)
#pragma unroll
        for (int j = 0; j < 4; j++) acc[i][j] = (f32x4){0.f, 0.f, 0.f, 0.f};

    stage(0, 0);
    for (int t = 0; t < 24; t++) {
        const int cur = t & 1;
        if (t < 23) { stage(t + 1, cur ^ 1); WAITVM(9); }
        else        { WAITVM(0); }
        SCHEDB(); BAR(); SCHEDB();
        {
            const char* bA = smem + cur * 4096;
            const char* bB = smem + 8192 + cur * 32768;
#pragma unroll
            for (int h = 0; h < 2; h++) {
                const int co = ((h * 4 + g) ^ (lm & 7)) * 16;
                bf16x8 a0 = *(const bf16x8*)(bA + lm * 128 + co);
                bf16x8 a1 = *(const bf16x8*)(bA + (16 + lm) * 128 + co);
#pragma unroll
                for (int ni = 0; ni < 4; ni++) {
                    bf16x8 bF = *(const bf16x8*)(bB + (w * 64 + ni * 16 + lm) * 128 + co);
                    acc[0][ni] = MF(a0, bF, acc[0][ni]);
                    acc[1][ni] = MF(a1, bF, acc[1][ni]);
                }
            }
        }
        SCHEDB(); BAR();
    }

#pragma unroll
    for (int ni = 0; ni < 4; ni++) {
        const int e = w * 64 + ni * 16 + lm;
        const float bo = bout[e];
#pragma unroll
        for (int mi = 0; mi < 2; mi++)
#pragma unroll
            for (int r = 0; r < 4; r++) {
                const int row = mi * 16 + g * 4 + r;
                const int64_t idx = ((int64_t)(b * S_ + s0 + row)) * D_ + e;
                out[idx] = acc[mi][ni][r] + gcn[idx] + bo;
            }
    }
}

extern "C" void kernel_launch(void* const* d_in, const int* in_sizes, int n_in,
                              void* d_out, int out_size, void* d_ws, size_t ws_size,
                              hipStream_t stream) {
    const float* adj  = (const float*)d_in[0];
    const float* gcn  = (const float*)d_in[1];
    const float* W    = (const float*)d_in[4];
    const float* bvec = (const float*)d_in[5];
    const float* Wout = (const float*)d_in[6];
    const float* bout = (const float*)d_in[7];
    float* out = (float*)d_out;

    const int64_t ADJ_N = (int64_t)3 * B_ * S_ * S_;
    unsigned short* adjBf  = (unsigned short*)d_ws;
    unsigned short* XbfT   = adjBf + ADJ_N;
    unsigned short* yAll   = XbfT + XSZ;        // 6 slices [B][S][D]
    unsigned short* yTh    = yAll + 6 * XSZ;    // 3 slices [B][D][S]
    unsigned short* Wbf    = yTh + 3 * XSZ;
    unsigned short* WoutBf = Wbf + 6 * D_ * D_;
    float* dInv            = (float*)(WoutBf + 6 * D_ * D_);  // [3][B][S]

    prep_adj_kernel<<<3 * B_ * S_ / 4, 256, 0, stream>>>(adj, adjBf, dInv);
    prep_x_kernel<<<dim3(8, 4, 32), 256, 0, stream>>>(gcn, XbfT);
    prep_w_kernel<<<384, 256, 0, stream>>>(W, Wout, Wbf, WoutBf);

    for (int h = 0; h < 3; h++) {
        const unsigned short* adjH = adjBf + (int64_t)h * B_ * S_ * S_;
        const float* dInvH = dInv + (int64_t)h * B_ * S_;
        layer_kernel<1><<<dim3(16, 32), 256, 0, stream>>>(
            adjH, XbfT,
            Wbf + (int64_t)(h * 2 + 0) * D_ * D_, bvec + (h * 2 + 0) * D_,
            dInvH, yAll + (int64_t)(h * 2 + 0) * XSZ, yTh + (int64_t)h * XSZ);
        layer_kernel<0><<<dim3(16, 32), 256, 0, stream>>>(
            adjH, yTh + (int64_t)h * XSZ,
            Wbf + (int64_t)(h * 2 + 1) * D_ * D_, bvec + (h * 2 + 1) * D_,
            dInvH, yAll + (int64_t)(h * 2 + 1) * XSZ, nullptr);
    }

    final_kernel<<<dim3(16, 32), 256, 0, stream>>>(yAll, WoutBf, gcn, bout, out);
}

// Round 5
// 131.982 us; speedup vs baseline: 2.5795x; 1.2809x over previous
//
#include <hip/hip_runtime.h>
#include <stdint.h>

#define S_ 512
#define B_ 32
#define D_ 256
#define XSZ ((int64_t)B_ * S_ * D_)

typedef __attribute__((ext_vector_type(8))) short bf16x8;
typedef __attribute__((ext_vector_type(4))) float f32x4;

#define WAITVM(n) asm volatile("s_waitcnt vmcnt(" #n ")" ::: "memory")
#define SCHEDB() __builtin_amdgcn_sched_barrier(0)
#define BAR() __builtin_amdgcn_s_barrier()

__device__ __forceinline__ unsigned short f2bf(float f) {
    union { float f; uint32_t u; } v; v.f = f;
    uint32_t r = v.u + 0x7FFFu + ((v.u >> 16) & 1u);
    return (unsigned short)(r >> 16);
}

__device__ __forceinline__ void gl_lds16(const unsigned short* g, void* lds_base) {
    __builtin_amdgcn_global_load_lds(
        (const __attribute__((address_space(1))) unsigned int*)g,
        (__attribute__((address_space(3))) unsigned int*)lds_base, 16, 0, 0);
}

__device__ __forceinline__ f32x4 MF(bf16x8 a, bf16x8 b, f32x4 c) {
    return __builtin_amdgcn_mfma_f32_16x16x32_bf16(a, b, c, 0, 0, 0);
}

// ---------- fused prep: [0,12288) adj  [12288,13312) xT  [13312,13696) W ----------
__global__ __launch_bounds__(256) void prep_kernel(
    const float* __restrict__ adj, const float* __restrict__ gcn,
    const float* __restrict__ W, const float* __restrict__ Wout,
    unsigned short* __restrict__ adjBf, float* __restrict__ dInv,
    unsigned short* __restrict__ XbfT,
    unsigned short* __restrict__ Wbf, unsigned short* __restrict__ WoutBf)
{
    __shared__ unsigned short T[64 * 65];
    const int bx = blockIdx.x;
    const int tid = threadIdx.x;

    if (bx < 12288) {  // ---- adj: bf16 + I, dInv ----
        const int flat = bx * 4 + (tid >> 6);
        const int lane = tid & 63;
        const float* src = adj + (int64_t)flat * S_ + lane * 8;
        float4 v0 = ((const float4*)src)[0];
        float4 v1 = ((const float4*)src)[1];
        float sum = v0.x + v0.y + v0.z + v0.w + v1.x + v1.y + v1.z + v1.w;
#pragma unroll
        for (int o = 1; o < 64; o <<= 1) sum += __shfl_xor(sum, o);
        const int s = flat & (S_ - 1);
        const int c0 = lane * 8;
        float e0 = v0.x + ((s == c0 + 0) ? 1.f : 0.f);
        float e1 = v0.y + ((s == c0 + 1) ? 1.f : 0.f);
        float e2 = v0.z + ((s == c0 + 2) ? 1.f : 0.f);
        float e3 = v0.w + ((s == c0 + 3) ? 1.f : 0.f);
        float e4 = v1.x + ((s == c0 + 4) ? 1.f : 0.f);
        float e5 = v1.y + ((s == c0 + 5) ? 1.f : 0.f);
        float e6 = v1.z + ((s == c0 + 6) ? 1.f : 0.f);
        float e7 = v1.w + ((s == c0 + 7) ? 1.f : 0.f);
        uint4 p;
        p.x = (uint32_t)f2bf(e0) | ((uint32_t)f2bf(e1) << 16);
        p.y = (uint32_t)f2bf(e2) | ((uint32_t)f2bf(e3) << 16);
        p.z = (uint32_t)f2bf(e4) | ((uint32_t)f2bf(e5) << 16);
        p.w = (uint32_t)f2bf(e6) | ((uint32_t)f2bf(e7) << 16);
        *(uint4*)&adjBf[(int64_t)flat * S_ + c0] = p;
        if (lane == 0) dInv[flat] = 1.0f / (sum + 1.0f);
    } else if (bx < 13312) {  // ---- gcn -> XbfT (transpose) ----
        const int idx = bx - 12288;
        const int s0 = (idx & 7) * 64, d0 = ((idx >> 3) & 3) * 64, b = idx >> 5;
        const int r = tid >> 2, seg = tid & 3;
        const float* src = gcn + ((int64_t)(b * S_ + s0 + r)) * D_ + d0 + seg * 16;
#pragma unroll
        for (int q = 0; q < 4; q++) {
            float4 v = ((const float4*)src)[q];
            unsigned short* t = &T[r * 65 + seg * 16 + q * 4];
            t[0] = f2bf(v.x); t[1] = f2bf(v.y); t[2] = f2bf(v.z); t[3] = f2bf(v.w);
        }
        __syncthreads();
        unsigned short tmp[16];
#pragma unroll
        for (int j = 0; j < 16; j++) tmp[j] = T[(seg * 16 + j) * 65 + r];
        unsigned short* dst = &XbfT[((int64_t)(b * D_ + d0 + r)) * S_ + s0 + seg * 16];
        ((uint4*)dst)[0] = ((uint4*)tmp)[0];
        ((uint4*)dst)[1] = ((uint4*)tmp)[1];
    } else {  // ---- W, Wout -> bf16 ----
        const int i = ((bx - 13312) * 256 + tid) * 4;
        {
            float4 v = *(const float4*)&W[i];
            uint2 p;
            p.x = (uint32_t)f2bf(v.x) | ((uint32_t)f2bf(v.y) << 16);
            p.y = (uint32_t)f2bf(v.z) | ((uint32_t)f2bf(v.w) << 16);
            *(uint2*)&Wbf[i] = p;
        }
        {
            float4 v = *(const float4*)&Wout[i];
            uint2 p;
            p.x = (uint32_t)f2bf(v.x) | ((uint32_t)f2bf(v.y) << 16);
            p.y = (uint32_t)f2bf(v.z) | ((uint32_t)f2bf(v.w) << 16);
            *(uint2*)&WoutBf[i] = p;
        }
    }
}

// ---------- layers (all 3 heads, one l): 768 blocks, 4 waves, tile 64s x 256d ----------
// bmm BK=64 (8 steps, 32 MFMA : 10 loads per wave), mm2 BK=32 (8 steps).
template<int L>
__global__ __launch_bounds__(256, 2) void layers_kernel(
    const unsigned short* __restrict__ adjBf,  // [3][B][S][S] (diag+1)
    const unsigned short* __restrict__ XbfT,   // [B][D][S]        (L==0 input)
    const unsigned short* __restrict__ yTh,    // [3][B][D][S]     (L==0 out / L==1 in)
    const unsigned short* __restrict__ Wbf,    // [6][D][D]
    const float* __restrict__ bvec,            // [6][D]
    const float* __restrict__ dInv,            // [3][B][S]
    unsigned short* __restrict__ yAll)         // [6][B][S][D]
{
    __shared__ __align__(16) char smem[81920];
    // bmm: bufA = smem + cur*8192 (64x128B), bufB = smem + 16384 + cur*32768 (256x128B)
    // mm2 overlay: Ps = smem[0..33792), Wst = smem + 36864 + cur*16384

    const int tid = threadIdx.x;
    const int w   = tid >> 6;
    const int l   = tid & 63;
    const int lm  = l & 15;
    const int g   = l >> 4;

    int flat = blockIdx.x;
    flat = (flat & 7) * 96 + (flat >> 3);      // XCD-chunked (768 = 8*96, bijective)
    const int h  = flat >> 8;
    const int rem = flat & 255;
    const int b  = rem >> 3;
    const int s0 = (rem & 7) * 64;

    const unsigned short* adjB = adjBf + (((int64_t)h * B_ + b) * S_ + s0) * S_;
    const unsigned short* xTB  = (L == 0) ? (XbfT + (int64_t)b * D_ * S_)
                                          : (yTh + ((int64_t)h * B_ + b) * D_ * S_);
    const unsigned short* Wl   = Wbf + (int64_t)(h * 2 + L) * D_ * D_;
    const float* bl            = bvec + (h * 2 + L) * D_;
    const float* dInvB         = dInv + ((int64_t)h * B_ + b) * S_ + s0;
    unsigned short* y          = yAll + (int64_t)(h * 2 + L) * XSZ + ((int64_t)(b * S_ + s0)) * D_;

    const int srow8  = l >> 3;                   // row-in-8
    const int schunk = ((l & 7) ^ (l >> 3)) * 8; // pre-swizzled source col (shorts)

    f32x4 acc[4][4];
#pragma unroll
    for (int i = 0; i < 4; i++)
#pragma unroll
        for (int j = 0; j < 4; j++) acc[i][j] = (f32x4){0.f, 0.f, 0.f, 0.f};

    auto stage = [&](int t0, int cur) {          // 10 gl_lds per wave
        char* bA = smem + cur * 8192;
        char* bB = smem + 16384 + cur * 32768;
        gl_lds16(&adjB[(w * 16 + srow8) * S_ + t0 + schunk], bA + w * 2048);
        gl_lds16(&adjB[(w * 16 + 8 + srow8) * S_ + t0 + schunk], bA + w * 2048 + 1024);
#pragma unroll
        for (int j = 0; j < 8; j++)
            gl_lds16(&xTB[(w * 64 + j * 8 + srow8) * S_ + t0 + schunk],
                     bB + w * 8192 + j * 1024);
    };
    auto compute = [&](int cur) {
        const char* bA = smem + cur * 8192;
        const char* bB = smem + 16384 + cur * 32768;
        __builtin_amdgcn_s_setprio(1);
#pragma unroll
        for (int h2 = 0; h2 < 2; h2++) {
            const int co = ((h2 * 4 + g) ^ (lm & 7)) * 16;
            bf16x8 aF[4];
#pragma unroll
            for (int mi = 0; mi < 4; mi++)
                aF[mi] = *(const bf16x8*)(bA + (mi * 16 + lm) * 128 + co);
#pragma unroll
            for (int ni = 0; ni < 4; ni++) {
                bf16x8 bF = *(const bf16x8*)(bB + (w * 64 + ni * 16 + lm) * 128 + co);
#pragma unroll
                for (int mi = 0; mi < 4; mi++)
                    acc[mi][ni] = MF(aF[mi], bF, acc[mi][ni]);
            }
        }
        __builtin_amdgcn_s_setprio(0);
    };

    // ---- bmm: P = (A+I)x ----
    stage(0, 0);
    for (int t = 0; t < 8; t++) {
        const int cur = t & 1;
        if (t < 7) { stage((t + 1) * 64, cur ^ 1); WAITVM(10); }
        else       { WAITVM(0); }
        SCHEDB(); BAR(); SCHEDB();
        compute(cur);
        SCHEDB(); BAR();
    }

    // ---- P -> Ps (bf16) ----
    unsigned short* Ps = (unsigned short*)smem;
#pragma unroll
    for (int mi = 0; mi < 4; mi++)
#pragma unroll
        for (int ni = 0; ni < 4; ni++) {
            const int col = w * 64 + ni * 16 + lm;
#pragma unroll
            for (int r = 0; r < 4; r++)
                Ps[(mi * 16 + g * 4 + r) * 264 + col] = f2bf(acc[mi][ni][r]);
        }

    const int sr16 = l >> 2;
    const int sc4  = ((l & 3) ^ ((l >> 3) & 3)) * 8;
    auto stageW = [&](int kc, int cur) {         // 4 gl_lds per wave
        char* bW = smem + 36864 + cur * 16384;
#pragma unroll
        for (int j = 0; j < 4; j++)
            gl_lds16(&Wl[(w * 64 + j * 16 + sr16) * D_ + kc * 32 + sc4],
                     bW + w * 4096 + j * 1024);
    };
    stageW(0, 0);
    __syncthreads();

    // ---- mm2: Q = P @ W^T ----
    f32x4 acc2[4][4];
#pragma unroll
    for (int i = 0; i < 4; i++)
#pragma unroll
        for (int j = 0; j < 4; j++) acc2[i][j] = (f32x4){0.f, 0.f, 0.f, 0.f};

    for (int kc = 0; kc < 8; kc++) {
        const int cur = kc & 1;
        if (kc < 7) { stageW(kc + 1, cur ^ 1); WAITVM(4); }
        else        { WAITVM(0); }
        SCHEDB(); BAR(); SCHEDB();
        {
            const char* bW = smem + 36864 + cur * 16384;
            const int co2 = (g ^ ((lm >> 1) & 3)) << 4;
            bf16x8 aF[4];
#pragma unroll
            for (int mi = 0; mi < 4; mi++)
                aF[mi] = *(const bf16x8*)&Ps[(mi * 16 + lm) * 264 + kc * 32 + g * 8];
            __builtin_amdgcn_s_setprio(1);
#pragma unroll
            for (int ni = 0; ni < 4; ni++) {
                bf16x8 bF = *(const bf16x8*)(bW + (w * 64 + ni * 16 + lm) * 64 + co2);
#pragma unroll
                for (int mi = 0; mi < 4; mi++)
                    acc2[mi][ni] = MF(aF[mi], bF, acc2[mi][ni]);
            }
            __builtin_amdgcn_s_setprio(0);
        }
        SCHEDB(); BAR();
    }

    // ---- epilogue: y = relu((Q + 2b) * dInv) ----
    float dv[4][4];
#pragma unroll
    for (int mi = 0; mi < 4; mi++)
#pragma unroll
        for (int r = 0; r < 4; r++)
            dv[mi][r] = dInvB[mi * 16 + g * 4 + r];

#pragma unroll
    for (int ni = 0; ni < 4; ni++) {
        const int col = w * 64 + ni * 16 + lm;
        const float bv = 2.0f * bl[col];
#pragma unroll
        for (int mi = 0; mi < 4; mi++)
#pragma unroll
            for (int r = 0; r < 4; r++) {
                float v = (acc2[mi][ni][r] + bv) * dv[mi][r];
                v = v > 0.f ? v : 0.f;
                Ps[(mi * 16 + g * 4 + r) * 264 + col] = f2bf(v);
            }
    }
    __syncthreads();

    // coalesced y store: 64 rows x 512B, 128B/thread
    {
        const int rr = tid >> 2, seg = (tid & 3) * 64;
        const uint4* srcp = (const uint4*)&Ps[rr * 264 + seg];
        uint4* dst = (uint4*)&y[rr * D_ + seg];
#pragma unroll
        for (int q = 0; q < 8; q++) dst[q] = srcp[q];
    }
    if (L == 0) {  // transposed yT for next layer's bmm
        unsigned short* yT = (unsigned short*)(yTh + ((int64_t)h * B_ + b) * D_ * S_);
        const int e = tid;
        unsigned short tmp[64];
#pragma unroll
        for (int s = 0; s < 64; s++) tmp[s] = Ps[s * 264 + e];
        uint4* dst = (uint4*)&yT[(int64_t)e * S_ + s0];
#pragma unroll
        for (int q = 0; q < 8; q++) dst[q] = ((uint4*)tmp)[q];
    }
}

// ---------- final: 256 blocks, tile 64s x 256e, K=1536 (24 steps of 64) ----------
__global__ __launch_bounds__(256, 2) void final_kernel(
    const unsigned short* __restrict__ yAll,
    const unsigned short* __restrict__ WoutBf,  // [256][1536]
    const float* __restrict__ gcn,
    const float* __restrict__ bout,
    float* __restrict__ out)
{
    __shared__ __align__(16) char smem[81920];

    const int tid = threadIdx.x;
    const int w   = tid >> 6;
    const int l   = tid & 63;
    const int lm  = l & 15;
    const int g   = l >> 4;

    int flat = blockIdx.x;
    flat = (flat & 7) * 32 + (flat >> 3);       // 256 = 8*32, bijective
    const int b  = flat >> 3;
    const int s0 = (flat & 7) * 64;

    const int srow8  = l >> 3;
    const int schunk = ((l & 7) ^ (l >> 3)) * 8;
    const unsigned short* yBase = yAll + (int64_t)(b * S_ + s0) * D_;

    auto stage = [&](int kc, int cur) {          // 10 gl_lds per wave
        char* bA = smem + cur * 8192;
        char* bB = smem + 16384 + cur * 32768;
        const int hl = kc >> 2;
        const int e0 = (kc & 3) * 64;
        gl_lds16(&yBase[(int64_t)hl * XSZ + (w * 16 + srow8) * D_ + e0 + schunk],
                 bA + w * 2048);
        gl_lds16(&yBase[(int64_t)hl * XSZ + (w * 16 + 8 + srow8) * D_ + e0 + schunk],
                 bA + w * 2048 + 1024);
#pragma unroll
        for (int j = 0; j < 8; j++)
            gl_lds16(&WoutBf[(w * 64 + j * 8 + srow8) * 1536 + kc * 64 + schunk],
                     bB + w * 8192 + j * 1024);
    };

    f32x4 acc[4][4];
#pragma unroll
    for (int i = 0; i < 4; i++)
#pragma unroll
        for (int j = 0; j < 4; j++) acc[i][j] = (f32x4){0.f, 0.f, 0.f, 0.f};

    stage(0, 0);
    for (int t = 0; t < 24; t++) {
        const int cur = t & 1;
        if (t < 23) { stage(t + 1, cur ^ 1); WAITVM(10); }
        else        { WAITVM(0); }
        SCHEDB(); BAR(); SCHEDB();
        {
            const char* bA = smem + cur * 8192;
            const char* bB = smem + 16384 + cur * 32768;
            __builtin_amdgcn_s_setprio(1);
#pragma unroll
            for (int h2 = 0; h2 < 2; h2++) {
                const int co = ((h2 * 4 + g) ^ (lm & 7)) * 16;
                bf16x8 aF[4];
#pragma unroll
                for (int mi = 0; mi < 4; mi++)
                    aF[mi] = *(const bf16x8*)(bA + (mi * 16 + lm) * 128 + co);
#pragma unroll
                for (int ni = 0; ni < 4; ni++) {
                    bf16x8 bF = *(const bf16x8*)(bB + (w * 64 + ni * 16 + lm) * 128 + co);
#pragma unroll
                    for (int mi = 0; mi < 4; mi++)
                        acc[mi][ni] = MF(aF[mi], bF, acc[mi][ni]);
                }
            }
            __builtin_amdgcn_s_setprio(0);
        }
        SCHEDB(); BAR();
    }

#pragma unroll
    for (int ni = 0; ni < 4; ni++) {
        const int e = w * 64 + ni * 16 + lm;
        const float bo = bout[e];
#pragma unroll
        for (int mi = 0; mi < 4; mi++)
#pragma unroll
            for (int r = 0; r < 4; r++) {
                const int row = mi * 16 + g * 4 + r;
                const int64_t idx = ((int64_t)(b * S_ + s0 + row)) * D_ + e;
                out[idx] = acc[mi][ni][r] + gcn[idx] + bo;
            }
    }
}

extern "C" void kernel_launch(void* const* d_in, const int* in_sizes, int n_in,
                              void* d_out, int out_size, void* d_ws, size_t ws_size,
                              hipStream_t stream) {
    const float* adj  = (const float*)d_in[0];
    const float* gcn  = (const float*)d_in[1];
    const float* W    = (const float*)d_in[4];
    const float* bvec = (const float*)d_in[5];
    const float* Wout = (const float*)d_in[6];
    const float* bout = (const float*)d_in[7];
    float* out = (float*)d_out;

    const int64_t ADJ_N = (int64_t)3 * B_ * S_ * S_;
    unsigned short* adjBf  = (unsigned short*)d_ws;
    unsigned short* XbfT   = adjBf + ADJ_N;
    unsigned short* yAll   = XbfT + XSZ;        // 6 slices [B][S][D]
    unsigned short* yTh    = yAll + 6 * XSZ;    // 3 slices [B][D][S]
    unsigned short* Wbf    = yTh + 3 * XSZ;
    unsigned short* WoutBf = Wbf + 6 * D_ * D_;
    float* dInv            = (float*)(WoutBf + 6 * D_ * D_);  // [3][B][S]

    prep_kernel<<<13696, 256, 0, stream>>>(adj, gcn, W, Wout,
                                           adjBf, dInv, XbfT, Wbf, WoutBf);
    layers_kernel<0><<<768, 256, 0, stream>>>(adjBf, XbfT, yTh, Wbf, bvec, dInv, yAll);
    layers_kernel<1><<<768, 256, 0, stream>>>(adjBf, XbfT, yTh, Wbf, bvec, dInv, yAll);
    final_kernel<<<256, 256, 0, stream>>>(yAll, WoutBf, gcn, bout, out);
}